// Round 6
// baseline (245.875 us; speedup 1.0000x reference)
//
#include <hip/hip_runtime.h>
#include <math.h>

#define B_SZ 16384
#define F_N 39
#define V_N 30000
#define D_N 16
#define K_SEL 20
#define FD 624     // F_N * D_N
#define KP0 640    // controller/GEMM0 K padded to multiple of 32
#define NCP 48     // controller GEMM padded N (>= 39, 3 n-tiles of 16)
#define N0 1024
#define N1 512
#define CBR 16     // batch rows per fused-controller block
#define ALD 648    // LDS row stride (u16): 16B-aligned; stride%128dw=4dw -> even bank spread

typedef unsigned short u16;
typedef __attribute__((ext_vector_type(8))) short bf16x8;
typedef __attribute__((ext_vector_type(8))) unsigned short u16x8;
typedef __attribute__((ext_vector_type(4))) float f32x4;
typedef __attribute__((ext_vector_type(4))) unsigned short u16x4;

__device__ __forceinline__ u16 f2bf(float v) {
    union { float f; unsigned u; } x; x.f = v;
    unsigned r = x.u + 0x7fff + ((x.u >> 16) & 1);   // RNE
    return (u16)(r >> 16);
}
__device__ __forceinline__ float bf2f(u16 v) {
    union { unsigned u; float f; } x; x.u = ((unsigned)v) << 16;
    return x.f;
}

#define GLD16(gp, lp) __builtin_amdgcn_global_load_lds( \
    (const __attribute__((address_space(1))) unsigned int*)(gp), \
    (__attribute__((address_space(3))) unsigned int*)(lp), 16, 0, 0)

// ---------------------------------------------------------------------------
// Prep kernels
// ---------------------------------------------------------------------------
__global__ void convert_kernel(const float* __restrict__ src, u16* __restrict__ dst,
                               int n_el)
{
    int i = blockIdx.x * blockDim.x + threadIdx.x;
    if (i < n_el) dst[i] = f2bf(src[i]);
}

// w0p[n][f*16+d] = bf16(w0[n][d*39+f]), zero-pad cols 624..639
__global__ void prep_w0_kernel(const float* __restrict__ w0, u16* __restrict__ w0p)
{
    int i = blockIdx.x * blockDim.x + threadIdx.x;
    if (i >= N0 * KP0) return;
    int n = i / KP0, kk = i - n * KP0;
    float v = 0.f;
    if (kk < FD) {
        int f = kk >> 4, d = kk & 15;
        v = w0[n * FD + d * F_N + f];
    }
    w0p[i] = f2bf(v);
}

// wcb[n][f*16+d] = bf16(w_c[n][d*39+f]), zero-pad n to 48 rows, k to 640
__global__ void prep_wc_kernel(const float* __restrict__ w_c, u16* __restrict__ wcb)
{
    int i = blockIdx.x * blockDim.x + threadIdx.x;
    if (i >= NCP * KP0) return;
    int n = i / KP0, kk = i - n * KP0;
    float v = 0.f;
    if (n < F_N && kk < FD) {
        int f = kk >> 4, d = kk & 15;
        v = w_c[n * FD + d * F_N + f];
    }
    wcb[i] = f2bf(v);
}

// pad controller bn params 39 -> 48
__global__ void pad_params_kernel(const float* __restrict__ b_c,
                                  const float* __restrict__ g_c,
                                  const float* __restrict__ be_c,
                                  float* __restrict__ bp, float* __restrict__ gp,
                                  float* __restrict__ bep)
{
    int n = threadIdx.x;
    bp[n]  = (n < F_N) ? b_c[n]  : 0.f;
    gp[n]  = (n < F_N) ? g_c[n]  : 0.f;
    bep[n] = (n < F_N) ? be_c[n] : 0.f;
}

// ---------------------------------------------------------------------------
// Fused controller: gather -> LDS, 16x48 MFMA GEMM split-K over 4 waves,
// LDS reduce, wave0 bn/softmax/top-K rank, all-wave select-scale -> zb.
// 256 thr / 16 batch rows / block; 1024 blocks -> 16 waves/CU.
// ---------------------------------------------------------------------------
__global__ __launch_bounds__(256) void fused_controller_kernel(
    const int* __restrict__ x, const float* __restrict__ emb_table,
    const u16* __restrict__ wcb, const float* __restrict__ bcp,
    const float* __restrict__ gcp, const float* __restrict__ becp,
    u16* __restrict__ zb)
{
    __shared__ __align__(16) u16 Al[CBR * ALD];   // gathered A, bf16  (20.7 KB)
    __shared__ float vv[CBR][49];                 // exp scores        (3.1 KB)
    __shared__ f32x4 part[4][64][3];              // split-K partials  (12 KB)
    __shared__ float selw[CBR][F_N];              // selected weights  (2.5 KB)

    const int t    = threadIdx.x;
    const int wave = t >> 6;
    const int lane = t & 63;
    const int b0   = blockIdx.x * CBR;

    // ---- gather: 624 (row,f) pairs over 256 threads; x reads coalesced ----
    for (int p = t; p < CBR * F_N; p += 256) {
        const int row = p / F_N;
        const int f   = p - row * F_N;
        const int xi  = x[b0 * F_N + p];
        const float4* src = (const float4*)(emb_table + (size_t)(xi + f * V_N) * D_N);
        float4 v0 = src[0], v1 = src[1], v2 = src[2], v3 = src[3];
        u16x8 o0 = { f2bf(v0.x), f2bf(v0.y), f2bf(v0.z), f2bf(v0.w),
                     f2bf(v1.x), f2bf(v1.y), f2bf(v1.z), f2bf(v1.w) };
        u16x8 o1 = { f2bf(v2.x), f2bf(v2.y), f2bf(v2.z), f2bf(v2.w),
                     f2bf(v3.x), f2bf(v3.y), f2bf(v3.z), f2bf(v3.w) };
        *(u16x8*)&Al[row * ALD + f * D_N]     = o0;
        *(u16x8*)&Al[row * ALD + f * D_N + 8] = o1;
    }
    __syncthreads();

    // ---- GEMM split-K: wave w covers k in [w*160, w*160+160) ----
    const int m = lane & 15;
    const int q = lane >> 4;
    f32x4 acc0 = {}, acc1 = {}, acc2 = {};
    {
        const u16* ap  = &Al[m * ALD + wave * 160 + q * 8];
        const u16* bp0 = wcb + (size_t)(0  + m) * KP0 + wave * 160 + q * 8;
        const u16* bp1 = wcb + (size_t)(16 + m) * KP0 + wave * 160 + q * 8;
        const u16* bp2 = wcb + (size_t)(32 + m) * KP0 + wave * 160 + q * 8;
        #pragma unroll
        for (int k = 0; k < 5; ++k) {
            bf16x8 af = *(const bf16x8*)ap;
            bf16x8 b0 = *(const bf16x8*)bp0;
            bf16x8 b1 = *(const bf16x8*)bp1;
            bf16x8 b2 = *(const bf16x8*)bp2;
            acc0 = __builtin_amdgcn_mfma_f32_16x16x32_bf16(af, b0, acc0, 0, 0, 0);
            acc1 = __builtin_amdgcn_mfma_f32_16x16x32_bf16(af, b1, acc1, 0, 0, 0);
            acc2 = __builtin_amdgcn_mfma_f32_16x16x32_bf16(af, b2, acc2, 0, 0, 0);
            ap += 32; bp0 += 32; bp1 += 32; bp2 += 32;
        }
    }
    part[wave][lane][0] = acc0;
    part[wave][lane][1] = acc1;
    part[wave][lane][2] = acc2;
    __syncthreads();

    // ---- wave 0: reduce + bn/relu + softmax + top-K rank ----
    if (wave == 0) {
        f32x4 r0 = part[0][lane][0] + part[1][lane][0] + part[2][lane][0] + part[3][lane][0];
        f32x4 r1 = part[0][lane][1] + part[1][lane][1] + part[2][lane][1] + part[3][lane][1];
        f32x4 r2 = part[0][lane][2] + part[1][lane][2] + part[2][lane][2] + part[3][lane][2];

        const float rs = rsqrtf(1.0f + 1e-5f);
        #pragma unroll
        for (int j = 0; j < 3; ++j) {
            const f32x4 a = (j == 0) ? r0 : (j == 1) ? r1 : r2;
            const int n = j * 16 + m;
            const float gn = gcp[n] * rs;
            const float bn = becp[n];
            const float bi = bcp[n];
            #pragma unroll
            for (int r = 0; r < 4; ++r)
                vv[q * 4 + r][n] = fmaxf(fmaf(gn, a[r] + bi, bn), 0.f);
        }
        // (same-wave LDS RAW: compiler inserts lgkmcnt waits)

        const int row = lane >> 2;   // 16 rows x 4 lanes
        const int fg  = lane & 3;
        float e[10];
        float mloc = -1e30f;
        #pragma unroll
        for (int it = 0; it < 10; ++it) {
            const int f = fg + 4 * it;
            if (f < F_N) { e[it] = vv[row][f]; mloc = fmaxf(mloc, e[it]); }
        }
        mloc = fmaxf(mloc, __shfl_xor(mloc, 1, 64));
        mloc = fmaxf(mloc, __shfl_xor(mloc, 2, 64));
        float sloc = 0.f;
        #pragma unroll
        for (int it = 0; it < 10; ++it) {
            const int f = fg + 4 * it;
            if (f < F_N) { e[it] = expf(e[it] - mloc); sloc += e[it]; }
        }
        sloc += __shfl_xor(sloc, 1, 64);
        sloc += __shfl_xor(sloc, 2, 64);
        const float inv = 1.f / sloc;
        #pragma unroll
        for (int it = 0; it < 10; ++it) {
            const int f = fg + 4 * it;
            if (f < F_N) vv[row][f] = e[it];
        }

        int rank[10] = {};
        for (int gg = 0; gg < F_N; ++gg) {
            const float o = vv[row][gg];
            #pragma unroll
            for (int it = 0; it < 10; ++it) {
                const int f = fg + 4 * it;
                if (f < F_N)
                    rank[it] += (o > e[it] || (o == e[it] && gg < f)) ? 1 : 0;
            }
        }
        #pragma unroll
        for (int it = 0; it < 10; ++it) {
            const int f = fg + 4 * it;
            if (f < F_N)
                selw[row][f] = (rank[it] < K_SEL) ? e[it] * inv : 0.f;
        }
    }
    __syncthreads();

    // ---- select-scale -> zb: 640 groups of 16 u16 (slot 39 = pad zeros) ----
    for (int gp = t; gp < CBR * 40; gp += 256) {
        const int row  = gp & 15;
        const int slot = gp >> 4;
        u16* dst = zb + (size_t)(b0 + row) * KP0 + slot * D_N;
        u16x8 o0 = {0,0,0,0,0,0,0,0}, o1 = {0,0,0,0,0,0,0,0};
        if (slot < F_N) {
            const float w = selw[row][slot];
            u16x8 a0 = *(u16x8*)&Al[row * ALD + slot * D_N];
            u16x8 a1 = *(u16x8*)&Al[row * ALD + slot * D_N + 8];
            #pragma unroll
            for (int k = 0; k < 8; ++k) {
                o0[k] = f2bf(bf2f(a0[k]) * w);
                o1[k] = f2bf(bf2f(a1[k]) * w);
            }
        }
        *(u16x8*)dst = o0;
        *(u16x8*)(dst + 8) = o1;
    }
}

// ---------------------------------------------------------------------------
// MFMA GEMM: C[M,N] = relu(bn(A[M,Kp] @ W[N,Kp]^T + bias)); 128x128 tile.
// Operand-swapped MFMA (D: m in lanes, n in regs) -> u16x4/float4 stores.
// M-panel on blockIdx.x (fastest) -> XCD-local A reuse.
// ---------------------------------------------------------------------------
template<int STORE_BF16>
__global__ __launch_bounds__(256) void gemm_mfma_bn_relu(
    const u16* __restrict__ A, const u16* __restrict__ W,
    const float* __restrict__ bias, const float* __restrict__ g,
    const float* __restrict__ be, void* __restrict__ Cout,
    int M, int N, int Kp)
{
    __shared__ __align__(16) u16 As[128 * 32];
    __shared__ __align__(16) u16 Bs[128 * 32];

    const int t    = threadIdx.x;
    const int wave = t >> 6;
    const int lane = t & 63;
    const int wm   = wave >> 1, wn = wave & 1;
    const int m0   = blockIdx.x * 128;
    const int n0   = blockIdx.y * 128;

    const int lr    = lane >> 2;
    const int swz_u = (lane & 3) ^ ((lane >> 3) & 3);
    const u16* gA0 = A + (size_t)(m0 + wave * 32 + lr) * Kp + swz_u * 8;
    const u16* gA1 = gA0 + 16 * (size_t)Kp;
    const u16* gB0 = W + (size_t)(n0 + wave * 32 + lr) * Kp + swz_u * 8;
    const u16* gB1 = gB0 + 16 * (size_t)Kp;
    u16* lA0 = &As[(wave * 32)      * 32];
    u16* lA1 = &As[(wave * 32 + 16) * 32];
    u16* lB0 = &Bs[(wave * 32)      * 32];
    u16* lB1 = &Bs[(wave * 32 + 16) * 32];

    const int q    = lane >> 4;
    const int lr16 = lane & 15;

    int aoff[4], boff[4];
    #pragma unroll
    for (int i = 0; i < 4; ++i) {
        int ra = wm * 64 + i * 16 + lr16;
        aoff[i] = ra * 32 + ((q ^ ((ra >> 1) & 3)) * 8);
        int rb = wn * 64 + i * 16 + lr16;
        boff[i] = rb * 32 + ((q ^ ((rb >> 1) & 3)) * 8);
    }

    f32x4 acc[4][4] = {};

    for (int k0 = 0; k0 < Kp; k0 += 32) {
        GLD16(gA0, lA0); GLD16(gA1, lA1);
        GLD16(gB0, lB0); GLD16(gB1, lB1);
        gA0 += 32; gA1 += 32; gB0 += 32; gB1 += 32;
        __syncthreads();

        bf16x8 af[4], bfr[4];
        #pragma unroll
        for (int i = 0; i < 4; ++i) af[i]  = *(const bf16x8*)&As[aoff[i]];
        #pragma unroll
        for (int j = 0; j < 4; ++j) bfr[j] = *(const bf16x8*)&Bs[boff[j]];

        // swapped operands: D[lane=m][reg=n] -> contiguous-n stores
        #pragma unroll
        for (int i = 0; i < 4; ++i)
            #pragma unroll
            for (int j = 0; j < 4; ++j)
                acc[i][j] = __builtin_amdgcn_mfma_f32_16x16x32_bf16(
                    bfr[j], af[i], acc[i][j], 0, 0, 0);
        __syncthreads();
    }

    const float rs = rsqrtf(1.0f + 1e-5f);
    #pragma unroll
    for (int j = 0; j < 4; ++j) {
        const int nb = n0 + wn * 64 + j * 16 + q * 4;
        const float4 bi4 = *(const float4*)&bias[nb];
        const float4 g4  = *(const float4*)&g[nb];
        const float4 be4 = *(const float4*)&be[nb];
        #pragma unroll
        for (int i = 0; i < 4; ++i) {
            const int m = m0 + wm * 64 + i * 16 + lr16;
            u16x4 ob;
            float4 of;
            #pragma unroll
            for (int r = 0; r < 4; ++r) {
                float v = acc[i][j][r] + (&bi4.x)[r];
                v = fmaxf(fmaf((&g4.x)[r] * rs, v, (&be4.x)[r]), 0.f);
                if (STORE_BF16) ob[r] = f2bf(v);
                else            (&of.x)[r] = v;
            }
            if (STORE_BF16)
                *(u16x4*)((u16*)Cout + (size_t)m * N + nb) = ob;
            else
                *(float4*)((float*)Cout + (size_t)m * N + nb) = of;
        }
    }
}

// ---------------------------------------------------------------------------
// out[b] = sigmoid(dot(h1b[b,:512], w_out) + b_out); one wave per row
// ---------------------------------------------------------------------------
__global__ __launch_bounds__(256) void out_kernel(
    const u16* __restrict__ h1b, const float* __restrict__ w_out,
    const float* __restrict__ b_out, float* __restrict__ out)
{
    const int wave = threadIdx.x >> 6;
    const int lane = threadIdx.x & 63;
    const int b = blockIdx.x * 4 + wave;
    const u16* row = h1b + (size_t)b * N1;
    float s = 0.f;
    #pragma unroll
    for (int i = 0; i < 8; ++i) {
        int k = lane + i * 64;
        s = fmaf(bf2f(row[k]), w_out[k], s);
    }
    #pragma unroll
    for (int off = 32; off; off >>= 1) s += __shfl_down(s, off, 64);
    if (lane == 0) out[b] = 1.f / (1.f + expf(-(s + b_out[0])));
}

// ---------------------------------------------------------------------------
extern "C" void kernel_launch(void* const* d_in, const int* in_sizes, int n_in,
                              void* d_out, int out_size, void* d_ws, size_t ws_size,
                              hipStream_t stream)
{
    const int*   x     = (const int*)  d_in[0];
    const float* emb   = (const float*)d_in[1];
    const float* w_c   = (const float*)d_in[2];
    const float* b_c   = (const float*)d_in[3];
    const float* g_c   = (const float*)d_in[4];
    const float* be_c  = (const float*)d_in[5];
    const float* w0    = (const float*)d_in[6];
    const float* b0    = (const float*)d_in[7];
    const float* g0    = (const float*)d_in[8];
    const float* be0   = (const float*)d_in[9];
    const float* w1    = (const float*)d_in[10];
    const float* b1    = (const float*)d_in[11];
    const float* g1    = (const float*)d_in[12];
    const float* be1   = (const float*)d_in[13];
    const float* w_out = (const float*)d_in[14];
    const float* b_out = (const float*)d_in[15];
    float* out = (float*)d_out;

    // workspace layout (~75 MB)
    u16*   zb    = (u16*)d_ws;                          // B*640*2  = 20.97 MB
    u16*   w0b   = zb    + (size_t)B_SZ * KP0;          // 1.31 MB
    u16*   h0b   = w0b   + (size_t)N0 * KP0;            // 33.55 MB
    u16*   w1b   = h0b   + (size_t)B_SZ * N0;           // 1.05 MB
    u16*   h1b   = w1b   + (size_t)N1 * N0;             // 16.78 MB
    u16*   wcb   = h1b   + (size_t)B_SZ * N1;           // 0.06 MB
    float* bcp   = (float*)(wcb + (size_t)NCP * KP0);
    float* gcp   = bcp + NCP;
    float* becp  = gcp + NCP;

    pad_params_kernel<<<1, NCP, 0, stream>>>(b_c, g_c, be_c, bcp, gcp, becp);
    prep_wc_kernel<<<(NCP * KP0 + 255) / 256, 256, 0, stream>>>(w_c, wcb);
    prep_w0_kernel<<<(N0 * KP0 + 255) / 256, 256, 0, stream>>>(w0, w0b);
    convert_kernel<<<(N1 * N0 + 255) / 256, 256, 0, stream>>>(w1, w1b, N1 * N0);

    fused_controller_kernel<<<B_SZ / CBR, 256, 0, stream>>>(
        x, emb, wcb, bcp, gcp, becp, zb);

    gemm_mfma_bn_relu<1><<<dim3(B_SZ / 128, N0 / 128), 256, 0, stream>>>(
        zb, w0b, b0, g0, be0, h0b, B_SZ, N0, KP0);
    gemm_mfma_bn_relu<1><<<dim3(B_SZ / 128, N1 / 128), 256, 0, stream>>>(
        h0b, w1b, b1, g1, be1, h1b, B_SZ, N1, N0);

    out_kernel<<<B_SZ / 4, 256, 0, stream>>>(h1b, w_out, b_out, out);
}

// Round 7
// 230.721 us; speedup vs baseline: 1.0657x; 1.0657x over previous
//
#include <hip/hip_runtime.h>
#include <math.h>

#define B_SZ 16384
#define F_N 39
#define V_N 30000
#define D_N 16
#define K_SEL 20
#define FD 624     // F_N * D_N
#define KP0 640    // controller/GEMM0 K padded to multiple of 32
#define NCP 48     // controller GEMM padded N (>= 39, 3 n-tiles of 16)
#define N0 1024
#define N1 512
#define CBR 16     // batch rows per fused-controller block
#define ALD 648    // LDS row stride (u16)

typedef unsigned short u16;
typedef __attribute__((ext_vector_type(8))) short bf16x8;
typedef __attribute__((ext_vector_type(8))) unsigned short u16x8;
typedef __attribute__((ext_vector_type(4))) float f32x4;
typedef __attribute__((ext_vector_type(4))) unsigned short u16x4;

__device__ __forceinline__ u16 f2bf(float v) {
    union { float f; unsigned u; } x; x.f = v;
    unsigned r = x.u + 0x7fff + ((x.u >> 16) & 1);   // RNE
    return (u16)(r >> 16);
}
__device__ __forceinline__ float bf2f(u16 v) {
    union { unsigned u; float f; } x; x.u = ((unsigned)v) << 16;
    return x.f;
}

#define GLD16(gp, lp) __builtin_amdgcn_global_load_lds( \
    (const __attribute__((address_space(1))) unsigned int*)(gp), \
    (__attribute__((address_space(3))) unsigned int*)(lp), 16, 0, 0)

// ---------------------------------------------------------------------------
// Merged prep: w0 permute+convert, w1 convert, wc permute+convert, bn params
// ---------------------------------------------------------------------------
#define PREP_W0 (N0 * KP0)                 // 655360
#define PREP_W1 (N1 * N0)                  // 524288
#define PREP_WC (NCP * KP0)                // 30720
#define PREP_TOT (PREP_W0 + PREP_W1 + PREP_WC + 3 * NCP)

__global__ __launch_bounds__(256) void prep_all_kernel(
    const float* __restrict__ w0, const float* __restrict__ w1,
    const float* __restrict__ w_c, const float* __restrict__ b_c,
    const float* __restrict__ g_c, const float* __restrict__ be_c,
    u16* __restrict__ w0b, u16* __restrict__ w1b, u16* __restrict__ wcb,
    float* __restrict__ bcp, float* __restrict__ gcp, float* __restrict__ becp)
{
    int i = blockIdx.x * blockDim.x + threadIdx.x;
    if (i < PREP_W0) {
        int n = i / KP0, kk = i - n * KP0;
        float v = 0.f;
        if (kk < FD) v = w0[n * FD + (kk & 15) * F_N + (kk >> 4)];
        w0b[i] = f2bf(v);
        return;
    }
    i -= PREP_W0;
    if (i < PREP_W1) { w1b[i] = f2bf(w1[i]); return; }
    i -= PREP_W1;
    if (i < PREP_WC) {
        int n = i / KP0, kk = i - n * KP0;
        float v = 0.f;
        if (n < F_N && kk < FD) v = w_c[n * FD + (kk & 15) * F_N + (kk >> 4)];
        wcb[i] = f2bf(v);
        return;
    }
    i -= PREP_WC;
    if (i < 3 * NCP) {
        int which = i / NCP, n = i - which * NCP;
        float v = 0.f;
        if (n < F_N) v = (which == 0) ? b_c[n] : (which == 1) ? g_c[n] : be_c[n];
        ((which == 0) ? bcp : (which == 1) ? gcp : becp)[n] = v;
    }
}

// ---------------------------------------------------------------------------
// Fused controller: gather -> LDS, 16x48 MFMA GEMM split-K over 4 waves,
// LDS reduce, wave0 bn/softmax/top-K rank, all-wave select-scale -> zb.
// ---------------------------------------------------------------------------
__global__ __launch_bounds__(256) void fused_controller_kernel(
    const int* __restrict__ x, const float* __restrict__ emb_table,
    const u16* __restrict__ wcb, const float* __restrict__ bcp,
    const float* __restrict__ gcp, const float* __restrict__ becp,
    u16* __restrict__ zb)
{
    __shared__ __align__(16) u16 Al[CBR * ALD];
    __shared__ float vv[CBR][49];
    __shared__ f32x4 part[4][64][3];
    __shared__ float selw[CBR][F_N];

    const int t    = threadIdx.x;
    const int wave = t >> 6;
    const int lane = t & 63;
    const int b0   = blockIdx.x * CBR;

    for (int p = t; p < CBR * F_N; p += 256) {
        const int row = p / F_N;
        const int f   = p - row * F_N;
        const int xi  = x[b0 * F_N + p];
        const float4* src = (const float4*)(emb_table + (size_t)(xi + f * V_N) * D_N);
        float4 v0 = src[0], v1 = src[1], v2 = src[2], v3 = src[3];
        u16x8 o0 = { f2bf(v0.x), f2bf(v0.y), f2bf(v0.z), f2bf(v0.w),
                     f2bf(v1.x), f2bf(v1.y), f2bf(v1.z), f2bf(v1.w) };
        u16x8 o1 = { f2bf(v2.x), f2bf(v2.y), f2bf(v2.z), f2bf(v2.w),
                     f2bf(v3.x), f2bf(v3.y), f2bf(v3.z), f2bf(v3.w) };
        *(u16x8*)&Al[row * ALD + f * D_N]     = o0;
        *(u16x8*)&Al[row * ALD + f * D_N + 8] = o1;
    }
    __syncthreads();

    const int m = lane & 15;
    const int q = lane >> 4;
    f32x4 acc0 = {}, acc1 = {}, acc2 = {};
    {
        const u16* ap  = &Al[m * ALD + wave * 160 + q * 8];
        const u16* bp0 = wcb + (size_t)(0  + m) * KP0 + wave * 160 + q * 8;
        const u16* bp1 = wcb + (size_t)(16 + m) * KP0 + wave * 160 + q * 8;
        const u16* bp2 = wcb + (size_t)(32 + m) * KP0 + wave * 160 + q * 8;
        #pragma unroll
        for (int k = 0; k < 5; ++k) {
            bf16x8 af = *(const bf16x8*)ap;
            bf16x8 b0 = *(const bf16x8*)bp0;
            bf16x8 b1 = *(const bf16x8*)bp1;
            bf16x8 b2 = *(const bf16x8*)bp2;
            acc0 = __builtin_amdgcn_mfma_f32_16x16x32_bf16(af, b0, acc0, 0, 0, 0);
            acc1 = __builtin_amdgcn_mfma_f32_16x16x32_bf16(af, b1, acc1, 0, 0, 0);
            acc2 = __builtin_amdgcn_mfma_f32_16x16x32_bf16(af, b2, acc2, 0, 0, 0);
            ap += 32; bp0 += 32; bp1 += 32; bp2 += 32;
        }
    }
    part[wave][lane][0] = acc0;
    part[wave][lane][1] = acc1;
    part[wave][lane][2] = acc2;
    __syncthreads();

    if (wave == 0) {
        f32x4 r0 = part[0][lane][0] + part[1][lane][0] + part[2][lane][0] + part[3][lane][0];
        f32x4 r1 = part[0][lane][1] + part[1][lane][1] + part[2][lane][1] + part[3][lane][1];
        f32x4 r2 = part[0][lane][2] + part[1][lane][2] + part[2][lane][2] + part[3][lane][2];

        const float rs = rsqrtf(1.0f + 1e-5f);
        #pragma unroll
        for (int j = 0; j < 3; ++j) {
            const f32x4 a = (j == 0) ? r0 : (j == 1) ? r1 : r2;
            const int n = j * 16 + m;
            const float gn = gcp[n] * rs;
            const float bn = becp[n];
            const float bi = bcp[n];
            #pragma unroll
            for (int r = 0; r < 4; ++r)
                vv[q * 4 + r][n] = fmaxf(fmaf(gn, a[r] + bi, bn), 0.f);
        }

        const int row = lane >> 2;
        const int fg  = lane & 3;
        float e[10];
        float mloc = -1e30f;
        #pragma unroll
        for (int it = 0; it < 10; ++it) {
            const int f = fg + 4 * it;
            if (f < F_N) { e[it] = vv[row][f]; mloc = fmaxf(mloc, e[it]); }
        }
        mloc = fmaxf(mloc, __shfl_xor(mloc, 1, 64));
        mloc = fmaxf(mloc, __shfl_xor(mloc, 2, 64));
        float sloc = 0.f;
        #pragma unroll
        for (int it = 0; it < 10; ++it) {
            const int f = fg + 4 * it;
            if (f < F_N) { e[it] = expf(e[it] - mloc); sloc += e[it]; }
        }
        sloc += __shfl_xor(sloc, 1, 64);
        sloc += __shfl_xor(sloc, 2, 64);
        const float inv = 1.f / sloc;
        #pragma unroll
        for (int it = 0; it < 10; ++it) {
            const int f = fg + 4 * it;
            if (f < F_N) vv[row][f] = e[it];
        }

        int rank[10] = {};
        for (int gg = 0; gg < F_N; ++gg) {
            const float o = vv[row][gg];
            #pragma unroll
            for (int it = 0; it < 10; ++it) {
                const int f = fg + 4 * it;
                if (f < F_N)
                    rank[it] += (o > e[it] || (o == e[it] && gg < f)) ? 1 : 0;
            }
        }
        #pragma unroll
        for (int it = 0; it < 10; ++it) {
            const int f = fg + 4 * it;
            if (f < F_N)
                selw[row][f] = (rank[it] < K_SEL) ? e[it] * inv : 0.f;
        }
    }
    __syncthreads();

    for (int gp = t; gp < CBR * 40; gp += 256) {
        const int row  = gp & 15;
        const int slot = gp >> 4;
        u16* dst = zb + (size_t)(b0 + row) * KP0 + slot * D_N;
        u16x8 o0 = {0,0,0,0,0,0,0,0}, o1 = {0,0,0,0,0,0,0,0};
        if (slot < F_N) {
            const float w = selw[row][slot];
            u16x8 a0 = *(u16x8*)&Al[row * ALD + slot * D_N];
            u16x8 a1 = *(u16x8*)&Al[row * ALD + slot * D_N + 8];
            #pragma unroll
            for (int k = 0; k < 8; ++k) {
                o0[k] = f2bf(bf2f(a0[k]) * w);
                o1[k] = f2bf(bf2f(a1[k]) * w);
            }
        }
        *(u16x8*)dst = o0;
        *(u16x8*)(dst + 8) = o1;
    }
}

// ---------------------------------------------------------------------------
// MFMA GEMM, 128x128 tile, BK=32, 16x16x32 bf16, global_load_lds staging.
// MODE 0: C = relu(bn(A@W^T+bias)) stored bf16.
// MODE 1: same activation, then fused dot with w_out -> atomicAdd row
//         partials into outp (no C store).
// ---------------------------------------------------------------------------
template<int MODE>
__global__ __launch_bounds__(256) void gemm_mfma_bn_relu(
    const u16* __restrict__ A, const u16* __restrict__ W,
    const float* __restrict__ bias, const float* __restrict__ g,
    const float* __restrict__ be, u16* __restrict__ Cout,
    int M, int N, int Kp,
    const float* __restrict__ w_out, float* __restrict__ outp)
{
    __shared__ __align__(16) u16 As[128 * 32];
    __shared__ __align__(16) u16 Bs[128 * 32];

    const int t    = threadIdx.x;
    const int wave = t >> 6;
    const int lane = t & 63;
    const int wm   = wave >> 1, wn = wave & 1;
    const int m0   = blockIdx.x * 128;   // M fastest -> XCD-local A reuse
    const int n0   = blockIdx.y * 128;

    const int lr    = lane >> 2;
    const int swz_u = (lane & 3) ^ ((lane >> 3) & 3);
    const u16* gA0 = A + (size_t)(m0 + wave * 32 + lr) * Kp + swz_u * 8;
    const u16* gA1 = gA0 + 16 * (size_t)Kp;
    const u16* gB0 = W + (size_t)(n0 + wave * 32 + lr) * Kp + swz_u * 8;
    const u16* gB1 = gB0 + 16 * (size_t)Kp;
    u16* lA0 = &As[(wave * 32)      * 32];
    u16* lA1 = &As[(wave * 32 + 16) * 32];
    u16* lB0 = &Bs[(wave * 32)      * 32];
    u16* lB1 = &Bs[(wave * 32 + 16) * 32];

    const int q    = lane >> 4;
    const int lr16 = lane & 15;

    int aoff[4], boff[4];
    #pragma unroll
    for (int i = 0; i < 4; ++i) {
        int ra = wm * 64 + i * 16 + lr16;
        aoff[i] = ra * 32 + ((q ^ ((ra >> 1) & 3)) * 8);
        int rb = wn * 64 + i * 16 + lr16;
        boff[i] = rb * 32 + ((q ^ ((rb >> 1) & 3)) * 8);
    }

    f32x4 acc[4][4] = {};

    for (int k0 = 0; k0 < Kp; k0 += 32) {
        GLD16(gA0, lA0); GLD16(gA1, lA1);
        GLD16(gB0, lB0); GLD16(gB1, lB1);
        gA0 += 32; gA1 += 32; gB0 += 32; gB1 += 32;
        __syncthreads();

        bf16x8 af[4], bfr[4];
        #pragma unroll
        for (int i = 0; i < 4; ++i) af[i]  = *(const bf16x8*)&As[aoff[i]];
        #pragma unroll
        for (int j = 0; j < 4; ++j) bfr[j] = *(const bf16x8*)&Bs[boff[j]];

        #pragma unroll
        for (int i = 0; i < 4; ++i)
            #pragma unroll
            for (int j = 0; j < 4; ++j)
                acc[i][j] = __builtin_amdgcn_mfma_f32_16x16x32_bf16(
                    af[i], bfr[j], acc[i][j], 0, 0, 0);
        __syncthreads();
    }

    const float rs = rsqrtf(1.0f + 1e-5f);
    if (MODE == 0) {
        #pragma unroll
        for (int j = 0; j < 4; ++j) {
            const int n = n0 + wn * 64 + j * 16 + lr16;
            const float bn_g = g[n] * rs;
            const float bn_b = be[n];
            const float bi   = bias[n];
            #pragma unroll
            for (int i = 0; i < 4; ++i) {
                const int mbase = m0 + wm * 64 + i * 16 + q * 4;
                #pragma unroll
                for (int r = 0; r < 4; ++r) {
                    float v = acc[i][j][r] + bi;
                    v = fmaxf(fmaf(bn_g, v, bn_b), 0.f);
                    Cout[(size_t)(mbase + r) * N + n] = f2bf(v);
                }
            }
        }
    } else {
        // fused final-layer dot: s[i][r] = sum_n relu(bn(.))*w_out[n]
        float s[4][4] = {};
        #pragma unroll
        for (int j = 0; j < 4; ++j) {
            const int n = n0 + wn * 64 + j * 16 + lr16;
            const float bn_g = g[n] * rs;
            const float bn_b = be[n];
            const float bi   = bias[n];
            const float wo   = w_out[n];
            #pragma unroll
            for (int i = 0; i < 4; ++i)
                #pragma unroll
                for (int r = 0; r < 4; ++r) {
                    float v = acc[i][j][r] + bi;
                    v = fmaxf(fmaf(bn_g, v, bn_b), 0.f);
                    s[i][r] = fmaf(v, wo, s[i][r]);
                }
        }
        // reduce over the 16 lanes (lr16) sharing the same rows
        #pragma unroll
        for (int i = 0; i < 4; ++i)
            #pragma unroll
            for (int r = 0; r < 4; ++r) {
                float v = s[i][r];
                v += __shfl_xor(v, 1, 64);
                v += __shfl_xor(v, 2, 64);
                v += __shfl_xor(v, 4, 64);
                v += __shfl_xor(v, 8, 64);
                s[i][r] = v;
            }
        if (lr16 == 0) {
            #pragma unroll
            for (int i = 0; i < 4; ++i) {
                const int mbase = m0 + wm * 64 + i * 16 + q * 4;
                #pragma unroll
                for (int r = 0; r < 4; ++r)
                    atomicAdd(&outp[mbase + r], s[i][r]);
            }
        }
    }
}

// ---------------------------------------------------------------------------
// out[b] = sigmoid(outp[b] + b_out)
// ---------------------------------------------------------------------------
__global__ __launch_bounds__(256) void sigmoid_kernel(
    const float* __restrict__ outp, const float* __restrict__ b_out,
    float* __restrict__ out)
{
    const int b = blockIdx.x * 256 + threadIdx.x;
    out[b] = 1.f / (1.f + expf(-(outp[b] + b_out[0])));
}

// ---------------------------------------------------------------------------
extern "C" void kernel_launch(void* const* d_in, const int* in_sizes, int n_in,
                              void* d_out, int out_size, void* d_ws, size_t ws_size,
                              hipStream_t stream)
{
    const int*   x     = (const int*)  d_in[0];
    const float* emb   = (const float*)d_in[1];
    const float* w_c   = (const float*)d_in[2];
    const float* b_c   = (const float*)d_in[3];
    const float* g_c   = (const float*)d_in[4];
    const float* be_c  = (const float*)d_in[5];
    const float* w0    = (const float*)d_in[6];
    const float* b0    = (const float*)d_in[7];
    const float* g0    = (const float*)d_in[8];
    const float* be0   = (const float*)d_in[9];
    const float* w1    = (const float*)d_in[10];
    const float* b1    = (const float*)d_in[11];
    const float* g1    = (const float*)d_in[12];
    const float* be1   = (const float*)d_in[13];
    const float* w_out = (const float*)d_in[14];
    const float* b_out = (const float*)d_in[15];
    float* out = (float*)d_out;

    // workspace layout (~57 MB)
    u16*   zb    = (u16*)d_ws;                          // B*640*2  = 20.97 MB
    u16*   w0b   = zb    + (size_t)B_SZ * KP0;          // 1.31 MB
    u16*   h0b   = w0b   + (size_t)N0 * KP0;            // 33.55 MB
    u16*   w1b   = h0b   + (size_t)B_SZ * N0;           // 1.05 MB
    u16*   wcb   = w1b   + (size_t)N1 * N0;             // 0.06 MB
    float* outp  = (float*)(wcb + (size_t)NCP * KP0);   // 64 KB
    float* bcp   = outp + B_SZ;
    float* gcp   = bcp + NCP;
    float* becp  = gcp + NCP;

    prep_all_kernel<<<(PREP_TOT + 255) / 256, 256, 0, stream>>>(
        w0, w1, w_c, b_c, g_c, be_c, w0b, w1b, wcb, bcp, gcp, becp);

    fused_controller_kernel<<<B_SZ / CBR, 256, 0, stream>>>(
        x, emb, wcb, bcp, gcp, becp, zb);

    gemm_mfma_bn_relu<0><<<dim3(B_SZ / 128, N0 / 128), 256, 0, stream>>>(
        zb, w0b, b0, g0, be0, h0b, B_SZ, N0, KP0, nullptr, nullptr);

    hipMemsetAsync(outp, 0, B_SZ * sizeof(float), stream);

    gemm_mfma_bn_relu<1><<<dim3(B_SZ / 128, N1 / 128), 256, 0, stream>>>(
        h0b, w1b, b1, g1, be1, nullptr, B_SZ, N1, N0, w_out, outp);

    sigmoid_kernel<<<B_SZ / 256, 256, 0, stream>>>(outp, b_out, out);
}

// Round 8
// 223.293 us; speedup vs baseline: 1.1011x; 1.0333x over previous
//
#include <hip/hip_runtime.h>
#include <math.h>

#define B_SZ 16384
#define F_N 39
#define V_N 30000
#define D_N 16
#define K_SEL 20
#define FD 624     // F_N * D_N
#define KP0 640    // controller/GEMM0 K padded to multiple of 32
#define NCP 48     // controller GEMM padded N (>= 39, 3 n-tiles of 16)
#define N0 1024
#define N1 512
#define CBR 16     // batch rows per fused-controller block
#define ALD 648    // LDS row stride (u16)

typedef unsigned short u16;
typedef __attribute__((ext_vector_type(8))) short bf16x8;
typedef __attribute__((ext_vector_type(8))) unsigned short u16x8;
typedef __attribute__((ext_vector_type(4))) float f32x4;
typedef __attribute__((ext_vector_type(4))) unsigned short u16x4;

__device__ __forceinline__ u16 f2bf(float v) {
    union { float f; unsigned u; } x; x.f = v;
    unsigned r = x.u + 0x7fff + ((x.u >> 16) & 1);   // RNE
    return (u16)(r >> 16);
}
__device__ __forceinline__ float bf2f(u16 v) {
    union { unsigned u; float f; } x; x.u = ((unsigned)v) << 16;
    return x.f;
}

#define GLD16(gp, lp) __builtin_amdgcn_global_load_lds( \
    (const __attribute__((address_space(1))) unsigned int*)(gp), \
    (__attribute__((address_space(3))) unsigned int*)(lp), 16, 0, 0)

// ---------------------------------------------------------------------------
// Merged prep: w0 permute+convert, w1 convert, wc permute+convert, bn params
// ---------------------------------------------------------------------------
#define PREP_W0 (N0 * KP0)                 // 655360
#define PREP_W1 (N1 * N0)                  // 524288
#define PREP_WC (NCP * KP0)                // 30720
#define PREP_TOT (PREP_W0 + PREP_W1 + PREP_WC + 3 * NCP)

__global__ __launch_bounds__(256) void prep_all_kernel(
    const float* __restrict__ w0, const float* __restrict__ w1,
    const float* __restrict__ w_c, const float* __restrict__ b_c,
    const float* __restrict__ g_c, const float* __restrict__ be_c,
    u16* __restrict__ w0b, u16* __restrict__ w1b, u16* __restrict__ wcb,
    float* __restrict__ bcp, float* __restrict__ gcp, float* __restrict__ becp)
{
    int i = blockIdx.x * blockDim.x + threadIdx.x;
    if (i < PREP_W0) {
        int n = i / KP0, kk = i - n * KP0;
        float v = 0.f;
        if (kk < FD) v = w0[n * FD + (kk & 15) * F_N + (kk >> 4)];
        w0b[i] = f2bf(v);
        return;
    }
    i -= PREP_W0;
    if (i < PREP_W1) { w1b[i] = f2bf(w1[i]); return; }
    i -= PREP_W1;
    if (i < PREP_WC) {
        int n = i / KP0, kk = i - n * KP0;
        float v = 0.f;
        if (n < F_N && kk < FD) v = w_c[n * FD + (kk & 15) * F_N + (kk >> 4)];
        wcb[i] = f2bf(v);
        return;
    }
    i -= PREP_WC;
    if (i < 3 * NCP) {
        int which = i / NCP, n = i - which * NCP;
        float v = 0.f;
        if (n < F_N) v = (which == 0) ? b_c[n] : (which == 1) ? g_c[n] : be_c[n];
        ((which == 0) ? bcp : (which == 1) ? gcp : becp)[n] = v;
    }
}

// ---------------------------------------------------------------------------
// Fused controller: gather -> LDS, 16x48 MFMA GEMM split-K over 4 waves,
// all-wave reduce, wave-sliced bn/softmax/top-K rank, select-scale -> zb.
// ---------------------------------------------------------------------------
__global__ __launch_bounds__(256) void fused_controller_kernel(
    const int* __restrict__ x, const float* __restrict__ emb_table,
    const u16* __restrict__ wcb, const float* __restrict__ bcp,
    const float* __restrict__ gcp, const float* __restrict__ becp,
    u16* __restrict__ zb)
{
    __shared__ __align__(16) u16 Al[CBR * ALD];
    __shared__ float vv[CBR][49];
    __shared__ f32x4 part[4][64][3];
    __shared__ float selw[CBR][F_N];

    const int t    = threadIdx.x;
    const int wave = t >> 6;
    const int lane = t & 63;
    const int b0   = blockIdx.x * CBR;

    // ---- gather 624 (row,f) pairs over 256 threads ----
    for (int p = t; p < CBR * F_N; p += 256) {
        const int row = p / F_N;
        const int f   = p - row * F_N;
        const int xi  = x[b0 * F_N + p];
        const float4* src = (const float4*)(emb_table + (size_t)(xi + f * V_N) * D_N);
        float4 v0 = src[0], v1 = src[1], v2 = src[2], v3 = src[3];
        u16x8 o0 = { f2bf(v0.x), f2bf(v0.y), f2bf(v0.z), f2bf(v0.w),
                     f2bf(v1.x), f2bf(v1.y), f2bf(v1.z), f2bf(v1.w) };
        u16x8 o1 = { f2bf(v2.x), f2bf(v2.y), f2bf(v2.z), f2bf(v2.w),
                     f2bf(v3.x), f2bf(v3.y), f2bf(v3.z), f2bf(v3.w) };
        *(u16x8*)&Al[row * ALD + f * D_N]     = o0;
        *(u16x8*)&Al[row * ALD + f * D_N + 8] = o1;
    }
    __syncthreads();

    // ---- GEMM split-K: wave w covers k in [w*160, w*160+160) ----
    const int m = lane & 15;
    const int q = lane >> 4;
    f32x4 acc0 = {}, acc1 = {}, acc2 = {};
    {
        const u16* ap  = &Al[m * ALD + wave * 160 + q * 8];
        const u16* bp0 = wcb + (size_t)(0  + m) * KP0 + wave * 160 + q * 8;
        const u16* bp1 = wcb + (size_t)(16 + m) * KP0 + wave * 160 + q * 8;
        const u16* bp2 = wcb + (size_t)(32 + m) * KP0 + wave * 160 + q * 8;
        #pragma unroll
        for (int k = 0; k < 5; ++k) {
            bf16x8 af = *(const bf16x8*)ap;
            bf16x8 b0 = *(const bf16x8*)bp0;
            bf16x8 b1 = *(const bf16x8*)bp1;
            bf16x8 b2 = *(const bf16x8*)bp2;
            acc0 = __builtin_amdgcn_mfma_f32_16x16x32_bf16(af, b0, acc0, 0, 0, 0);
            acc1 = __builtin_amdgcn_mfma_f32_16x16x32_bf16(af, b1, acc1, 0, 0, 0);
            acc2 = __builtin_amdgcn_mfma_f32_16x16x32_bf16(af, b2, acc2, 0, 0, 0);
            ap += 32; bp0 += 32; bp1 += 32; bp2 += 32;
        }
    }
    part[wave][lane][0] = acc0;
    part[wave][lane][1] = acc1;
    part[wave][lane][2] = acc2;
    __syncthreads();

    // ---- all waves reduce; wave w writes bn rows 4w..4w+3 (q == wave) ----
    {
        f32x4 r0 = part[0][lane][0] + part[1][lane][0] + part[2][lane][0] + part[3][lane][0];
        f32x4 r1 = part[0][lane][1] + part[1][lane][1] + part[2][lane][1] + part[3][lane][1];
        f32x4 r2 = part[0][lane][2] + part[1][lane][2] + part[2][lane][2] + part[3][lane][2];

        const float rs = rsqrtf(1.0f + 1e-5f);
        if (q == wave) {
            #pragma unroll
            for (int j = 0; j < 3; ++j) {
                const f32x4 a = (j == 0) ? r0 : (j == 1) ? r1 : r2;
                const int n = j * 16 + m;
                const float gn = gcp[n] * rs;
                const float bn = becp[n];
                const float bi = bcp[n];
                #pragma unroll
                for (int r = 0; r < 4; ++r)
                    vv[wave * 4 + r][n] = fmaxf(fmaf(gn, a[r] + bi, bn), 0.f);
            }
        }
    }
    __syncthreads();

    // ---- softmax + top-K rank: 16 lanes per row, 3 fields per lane ----
    {
        const int row = wave * 4 + (lane >> 4);
        const int fl  = lane & 15;
        float e[3] = {0.f, 0.f, 0.f};
        float mloc = -1e30f;
        #pragma unroll
        for (int it = 0; it < 3; ++it) {
            const int f = fl + 16 * it;
            if (f < F_N) { e[it] = vv[row][f]; mloc = fmaxf(mloc, e[it]); }
        }
        mloc = fmaxf(mloc, __shfl_xor(mloc, 1, 64));
        mloc = fmaxf(mloc, __shfl_xor(mloc, 2, 64));
        mloc = fmaxf(mloc, __shfl_xor(mloc, 4, 64));
        mloc = fmaxf(mloc, __shfl_xor(mloc, 8, 64));
        float sloc = 0.f;
        #pragma unroll
        for (int it = 0; it < 3; ++it) {
            const int f = fl + 16 * it;
            if (f < F_N) { e[it] = expf(e[it] - mloc); sloc += e[it]; }
        }
        sloc += __shfl_xor(sloc, 1, 64);
        sloc += __shfl_xor(sloc, 2, 64);
        sloc += __shfl_xor(sloc, 4, 64);
        sloc += __shfl_xor(sloc, 8, 64);
        const float inv = 1.f / sloc;
        #pragma unroll
        for (int it = 0; it < 3; ++it) {
            const int f = fl + 16 * it;
            if (f < F_N) vv[row][f] = e[it];
        }

        int rank[3] = {};
        for (int gg = 0; gg < F_N; ++gg) {
            const float o = vv[row][gg];
            #pragma unroll
            for (int it = 0; it < 3; ++it) {
                const int f = fl + 16 * it;
                if (f < F_N)
                    rank[it] += (o > e[it] || (o == e[it] && gg < f)) ? 1 : 0;
            }
        }
        #pragma unroll
        for (int it = 0; it < 3; ++it) {
            const int f = fl + 16 * it;
            if (f < F_N)
                selw[row][f] = (rank[it] < K_SEL) ? e[it] * inv : 0.f;
        }
    }
    __syncthreads();

    // ---- select-scale -> zb: 640 groups of 16 u16 (slot 39 = pad zeros) ----
    for (int gp = t; gp < CBR * 40; gp += 256) {
        const int row  = gp & 15;
        const int slot = gp >> 4;
        u16* dst = zb + (size_t)(b0 + row) * KP0 + slot * D_N;
        u16x8 o0 = {0,0,0,0,0,0,0,0}, o1 = {0,0,0,0,0,0,0,0};
        if (slot < F_N) {
            const float w = selw[row][slot];
            u16x8 a0 = *(u16x8*)&Al[row * ALD + slot * D_N];
            u16x8 a1 = *(u16x8*)&Al[row * ALD + slot * D_N + 8];
            #pragma unroll
            for (int k = 0; k < 8; ++k) {
                o0[k] = f2bf(bf2f(a0[k]) * w);
                o1[k] = f2bf(bf2f(a1[k]) * w);
            }
        }
        *(u16x8*)dst = o0;
        *(u16x8*)(dst + 8) = o1;
    }
}

// ---------------------------------------------------------------------------
// MFMA GEMM, 128x128 tile, BK=32, double-buffered LDS, ONE barrier/K-iter:
// stage tile k+1 into alt buffer after the barrier, before MFMA of tile k,
// so GLD latency overlaps MFMA. MODE 0: store bf16 C. MODE 1: fused w_out
// dot + atomicAdd row partials.
// ---------------------------------------------------------------------------
template<int MODE>
__global__ __launch_bounds__(256) void gemm_mfma_bn_relu(
    const u16* __restrict__ A, const u16* __restrict__ W,
    const float* __restrict__ bias, const float* __restrict__ g,
    const float* __restrict__ be, u16* __restrict__ Cout,
    int M, int N, int Kp,
    const float* __restrict__ w_out, float* __restrict__ outp)
{
    __shared__ __align__(16) u16 As[2][128 * 32];
    __shared__ __align__(16) u16 Bs[2][128 * 32];

    const int t    = threadIdx.x;
    const int wave = t >> 6;
    const int lane = t & 63;
    const int wm   = wave >> 1, wn = wave & 1;
    const int m0   = blockIdx.x * 128;   // M fastest -> XCD-local A reuse
    const int n0   = blockIdx.y * 128;

    const int lr    = lane >> 2;
    const int swz_u = (lane & 3) ^ ((lane >> 3) & 3);
    const u16* gA0 = A + (size_t)(m0 + wave * 32 + lr) * Kp + swz_u * 8;
    const u16* gB0 = W + (size_t)(n0 + wave * 32 + lr) * Kp + swz_u * 8;
    const size_t kstep16 = 16 * (size_t)Kp;
    const int oA0 = (wave * 32) * 32;
    const int oA1 = (wave * 32 + 16) * 32;

    const int q    = lane >> 4;
    const int lr16 = lane & 15;

    int aoff[4], boff[4];
    #pragma unroll
    for (int i = 0; i < 4; ++i) {
        int ra = wm * 64 + i * 16 + lr16;
        aoff[i] = ra * 32 + ((q ^ ((ra >> 1) & 3)) * 8);
        int rb = wn * 64 + i * 16 + lr16;
        boff[i] = rb * 32 + ((q ^ ((rb >> 1) & 3)) * 8);
    }

    // prologue: stage tile 0 into buffer 0
    GLD16(gA0,           &As[0][oA0]);
    GLD16(gA0 + kstep16, &As[0][oA1]);
    GLD16(gB0,           &Bs[0][oA0]);
    GLD16(gB0 + kstep16, &Bs[0][oA1]);
    gA0 += 32; gB0 += 32;

    f32x4 acc[4][4] = {};
    int buf = 0;

    for (int k0 = 0; k0 < Kp; k0 += 32) {
        __syncthreads();   // vmcnt(0) drain: buf filled; alt buf free of readers
        if (k0 + 32 < Kp) {
            GLD16(gA0,           &As[buf ^ 1][oA0]);
            GLD16(gA0 + kstep16, &As[buf ^ 1][oA1]);
            GLD16(gB0,           &Bs[buf ^ 1][oA0]);
            GLD16(gB0 + kstep16, &Bs[buf ^ 1][oA1]);
            gA0 += 32; gB0 += 32;
        }

        bf16x8 af[4], bfr[4];
        #pragma unroll
        for (int i = 0; i < 4; ++i) af[i]  = *(const bf16x8*)&As[buf][aoff[i]];
        #pragma unroll
        for (int j = 0; j < 4; ++j) bfr[j] = *(const bf16x8*)&Bs[buf][boff[j]];

        #pragma unroll
        for (int i = 0; i < 4; ++i)
            #pragma unroll
            for (int j = 0; j < 4; ++j)
                acc[i][j] = __builtin_amdgcn_mfma_f32_16x16x32_bf16(
                    af[i], bfr[j], acc[i][j], 0, 0, 0);
        buf ^= 1;
    }

    const float rs = rsqrtf(1.0f + 1e-5f);
    if (MODE == 0) {
        #pragma unroll
        for (int j = 0; j < 4; ++j) {
            const int n = n0 + wn * 64 + j * 16 + lr16;
            const float bn_g = g[n] * rs;
            const float bn_b = be[n];
            const float bi   = bias[n];
            #pragma unroll
            for (int i = 0; i < 4; ++i) {
                const int mbase = m0 + wm * 64 + i * 16 + q * 4;
                #pragma unroll
                for (int r = 0; r < 4; ++r) {
                    float v = acc[i][j][r] + bi;
                    v = fmaxf(fmaf(bn_g, v, bn_b), 0.f);
                    Cout[(size_t)(mbase + r) * N + n] = f2bf(v);
                }
            }
        }
    } else {
        float s[4][4] = {};
        #pragma unroll
        for (int j = 0; j < 4; ++j) {
            const int n = n0 + wn * 64 + j * 16 + lr16;
            const float bn_g = g[n] * rs;
            const float bn_b = be[n];
            const float bi   = bias[n];
            const float wo   = w_out[n];
            #pragma unroll
            for (int i = 0; i < 4; ++i)
                #pragma unroll
                for (int r = 0; r < 4; ++r) {
                    float v = acc[i][j][r] + bi;
                    v = fmaxf(fmaf(bn_g, v, bn_b), 0.f);
                    s[i][r] = fmaf(v, wo, s[i][r]);
                }
        }
        #pragma unroll
        for (int i = 0; i < 4; ++i)
            #pragma unroll
            for (int r = 0; r < 4; ++r) {
                float v = s[i][r];
                v += __shfl_xor(v, 1, 64);
                v += __shfl_xor(v, 2, 64);
                v += __shfl_xor(v, 4, 64);
                v += __shfl_xor(v, 8, 64);
                s[i][r] = v;
            }
        if (lr16 == 0) {
            #pragma unroll
            for (int i = 0; i < 4; ++i) {
                const int mbase = m0 + wm * 64 + i * 16 + q * 4;
                #pragma unroll
                for (int r = 0; r < 4; ++r)
                    atomicAdd(&outp[mbase + r], s[i][r]);
            }
        }
    }
}

// ---------------------------------------------------------------------------
// out[b] = sigmoid(outp[b] + b_out)
// ---------------------------------------------------------------------------
__global__ __launch_bounds__(256) void sigmoid_kernel(
    const float* __restrict__ outp, const float* __restrict__ b_out,
    float* __restrict__ out)
{
    const int b = blockIdx.x * 256 + threadIdx.x;
    out[b] = 1.f / (1.f + expf(-(outp[b] + b_out[0])));
}

// ---------------------------------------------------------------------------
extern "C" void kernel_launch(void* const* d_in, const int* in_sizes, int n_in,
                              void* d_out, int out_size, void* d_ws, size_t ws_size,
                              hipStream_t stream)
{
    const int*   x     = (const int*)  d_in[0];
    const float* emb   = (const float*)d_in[1];
    const float* w_c   = (const float*)d_in[2];
    const float* b_c   = (const float*)d_in[3];
    const float* g_c   = (const float*)d_in[4];
    const float* be_c  = (const float*)d_in[5];
    const float* w0    = (const float*)d_in[6];
    const float* b0    = (const float*)d_in[7];
    const float* g0    = (const float*)d_in[8];
    const float* be0   = (const float*)d_in[9];
    const float* w1    = (const float*)d_in[10];
    const float* b1    = (const float*)d_in[11];
    const float* g1    = (const float*)d_in[12];
    const float* be1   = (const float*)d_in[13];
    const float* w_out = (const float*)d_in[14];
    const float* b_out = (const float*)d_in[15];
    float* out = (float*)d_out;

    // workspace layout (~57 MB)
    u16*   zb    = (u16*)d_ws;                          // B*640*2  = 20.97 MB
    u16*   w0b   = zb    + (size_t)B_SZ * KP0;          // 1.31 MB
    u16*   h0b   = w0b   + (size_t)N0 * KP0;            // 33.55 MB
    u16*   w1b   = h0b   + (size_t)B_SZ * N0;           // 1.05 MB
    u16*   wcb   = w1b   + (size_t)N1 * N0;             // 0.06 MB
    float* outp  = (float*)(wcb + (size_t)NCP * KP0);   // 64 KB
    float* bcp   = outp + B_SZ;
    float* gcp   = bcp + NCP;
    float* becp  = gcp + NCP;

    prep_all_kernel<<<(PREP_TOT + 255) / 256, 256, 0, stream>>>(
        w0, w1, w_c, b_c, g_c, be_c, w0b, w1b, wcb, bcp, gcp, becp);

    fused_controller_kernel<<<B_SZ / CBR, 256, 0, stream>>>(
        x, emb, wcb, bcp, gcp, becp, zb);

    gemm_mfma_bn_relu<0><<<dim3(B_SZ / 128, N0 / 128), 256, 0, stream>>>(
        zb, w0b, b0, g0, be0, h0b, B_SZ, N0, KP0, nullptr, nullptr);

    hipMemsetAsync(outp, 0, B_SZ * sizeof(float), stream);

    gemm_mfma_bn_relu<1><<<dim3(B_SZ / 128, N1 / 128), 256, 0, stream>>>(
        h0b, w1b, b1, g1, be1, nullptr, B_SZ, N1, N0, w_out, outp);

    sigmoid_kernel<<<B_SZ / 256, 256, 0, stream>>>(outp, b_out, out);
}